// Round 8
// baseline (88.941 us; speedup 1.0000x reference)
//
#include <hip/hip_runtime.h>

// SSIM fused: [16,1,1024,1024] fp32, 11-tap separable Gaussian.
// Software-pipelined: per stage, ONE barrier; between barriers a wave does
//   V-blur(st+1) -> LDS buf^1  (global loads + VALU + ds_write)
//   H-blur(st)   <- LDS buf    (ds_read_b128 + FMA + SSIM epilogue)
// so VALU / LDS / VMEM overlap within a single wave. 32 KB dbuf LDS.
// Aligned power-of-2 run mapping keeps b128 banks conflict-free.
// No min-occupancy launch_bounds arg (r5/r6: it forces spills).
// Deterministic two-stage reduction -> d_out[0].

typedef float f4 __attribute__((ext_vector_type(4)));

#define W      1024
#define H      1024
#define NIMG   16
#define HALO   5
#define BX     128                 // threads = LDS slots (input cols) per block
#define OUTW   118                 // output cols per block
#define RPS    8                   // rows per stage
#define NSTG   4                   // stages per block
#define TH     (RPS*NSTG)          // 32 output rows per block
#define GX     9                   // ceil(1024/118)
#define GY     (H/TH)              // 32
#define NBLK   (GX*GY*NIMG)        // 4608

__device__ __forceinline__ int swz(int s) { return s ^ ((s >> 3) & 7); }

template<bool INT>
__device__ __forceinline__ f4 load_ch(const float* __restrict__ p1,
                                      const float* __restrict__ p2,
                                      int j, int c, bool cOK)
{
    float a, b;
    if (INT) {
        a = p1[(size_t)j * W + c];
        b = p2[(size_t)j * W + c];
    } else {
        const bool ok = cOK && ((unsigned)j < H);
        a = ok ? p1[(size_t)j * W + c] : 0.0f;
        b = ok ? p2[(size_t)j * W + c] : 0.0f;
    }
    f4 v;
    v.x = a; v.y = b;
    v.z = fmaf(a, a, b * b);
    v.w = a * b;
    return v;
}

template<bool INT>
__device__ __forceinline__ void vstage(const float* __restrict__ p1,
                                       const float* __restrict__ p2,
                                       const float* __restrict__ w,
                                       int c, bool cOK, int rbase,
                                       f4 (&ring)[11], f4 (*buf)[BX], int ws_)
{
#pragma unroll
    for (int rr = 0; rr < RPS; ++rr) {
#pragma unroll
        for (int k = 0; k < 10; ++k) ring[k] = ring[k + 1];
        ring[10] = load_ch<INT>(p1, p2, rbase + rr, c, cOK);

        f4 acc = w[5] * ring[5];
#pragma unroll
        for (int k = 0; k < 5; ++k)
            acc += w[k] * (ring[k] + ring[10 - k]);

        buf[rr][ws_] = acc;
    }
}

template<bool INT>
__device__ float tile(const float* __restrict__ p1,
                      const float* __restrict__ p2,
                      const float* __restrict__ w,
                      int cb, int r0, int t,
                      f4 (*lds)[RPS][BX])
{
    const int  c   = cb + t;                 // this thread's input col
    const bool cOK = INT || ((unsigned)c < W);

    // ring[1..10] <- rows r0-5 .. r0+4 (packed 4 channels)
    f4 ring[11];
#pragma unroll
    for (int k = 0; k < 10; ++k)
        ring[k + 1] = load_ch<INT>(p1, p2, r0 - HALO + k, c, cOK);

    // h-task mapping (power-of-2, phase-group aligned)
    const int  q   = t >> 4;                 // staged row index 0..7
    const int  run = t & 15;                 // column run index
    const int  S0  = 8 * run;                // first LDS slot of run
    const bool hT  = (run < 15);             // run 15 idle in H phase
    const int  ws_ = swz(t);                 // v-phase write slot

    // prologue: stage 0 into buf 0
    vstage<INT>(p1, p2, w, c, cOK, r0 + HALO, ring, lds[0], ws_);
    __syncthreads();

    float tsum = 0.0f;

    for (int st = 0; st < NSTG; ++st) {
        // ---- V phase for next stage (other buffer) ----
        if (st + 1 < NSTG)
            vstage<INT>(p1, p2, w, c, cOK, r0 + (st + 1) * RPS + HALO,
                        ring, lds[(st + 1) & 1], ws_);

        // ---- H phase for current stage ----
        if (hT) {
            f4 (*buf)[BX] = lds[st & 1];
            f4 o[8] = {};
#pragma unroll
            for (int i = 0; i < 18; ++i) {
                int sIdx = S0 + i;                       // run14: up to 129
                sIdx = (sIdx < BX) ? sIdx : (BX - 1);    // clamp: feeds only invalid outs
                const f4 u = buf[q][swz(sIdx)];
#pragma unroll
                for (int oo = 0; oo < 8; ++oo) {
                    const int k = i - oo;
                    if (k >= 0 && k < 11)
                        o[oo] += w[k] * u;
                }
            }

            const float C1f = 0.0001f, C2f = 0.0009f;
#pragma unroll
            for (int oo = 0; oo < 8; ++oo) {
                const int rel = S0 + oo;                 // rel output col
                const bool valid = (rel < OUTW) &&
                                   (INT || (cb + HALO + rel) < W);
                if (valid) {
                    const float m1 = o[oo].x, m2 = o[oo].y;
                    const float qq = o[oo].z, pp = o[oo].w;
                    const float mu12 = m1 * m2, m1s = m1 * m1, m2s = m2 * m2;
                    const float s12 = pp - mu12;
                    const float ssq = qq - m1s - m2s;
                    const float num = (2.f * mu12 + C1f) * (2.f * s12 + C2f);
                    const float den = (m1s + m2s + C1f) * (ssq + C2f);
                    tsum += num * __builtin_amdgcn_rcpf(den);
                }
            }
        }
        __syncthreads();   // protects buf^1 (written above) for next iteration
    }
    return tsum;
}

__global__ __launch_bounds__(BX) void ssim_main(const float* __restrict__ img1,
                                                const float* __restrict__ img2,
                                                const float* __restrict__ win,
                                                float* __restrict__ partials)
{
    __shared__ f4 lds[2][RPS][BX];           // 32 KB, double-buffered

    const int t  = threadIdx.x;
    const int n  = blockIdx.z;
    const int bx = blockIdx.x;
    const int gy = blockIdx.y;
    const int cb = bx * OUTW - HALO;         // input col of LDS slot 0
    const int r0 = gy * TH;

    const float* __restrict__ p1 = img1 + (size_t)n * (size_t)(W * H);
    const float* __restrict__ p2 = img2 + (size_t)n * (size_t)(W * H);

    float w[11];
#pragma unroll
    for (int k = 0; k < 11; ++k)
        w[k] = __int_as_float(__builtin_amdgcn_readfirstlane(__float_as_int(win[k])));

    const bool interior = (cb >= 0) && (cb + BX <= W) &&
                          (r0 >= HALO) && (r0 + TH - 1 + HALO < H);

    float tsum = interior ? tile<true >(p1, p2, w, cb, r0, t, lds)
                          : tile<false>(p1, p2, w, cb, r0, t, lds);

    // block reduction (2 waves of 64); reuse staging LDS as scratch
#pragma unroll
    for (int off = 32; off > 0; off >>= 1)
        tsum += __shfl_down(tsum, off, 64);

    float* red = (float*)lds;                // safe: trailing barrier in tile()
    if ((t & 63) == 0) red[t >> 6] = tsum;
    __syncthreads();
    if (t == 0)
        partials[((size_t)n * GY + gy) * GX + bx] = red[0] + red[1];
}

__global__ __launch_bounds__(256) void ssim_finalize(const float* __restrict__ partials,
                                                     float* __restrict__ out)
{
    double s = 0.0;
    for (int i = threadIdx.x; i < NBLK; i += 256) s += (double)partials[i];
#pragma unroll
    for (int off = 32; off > 0; off >>= 1)
        s += __shfl_down(s, off, 64);

    __shared__ double ws[4];
    if ((threadIdx.x & 63) == 0) ws[threadIdx.x >> 6] = s;
    __syncthreads();
    if (threadIdx.x == 0) {
        const double tt = ws[0] + ws[1] + ws[2] + ws[3];
        out[0] = (float)(tt / (double)((size_t)NIMG * W * H));
    }
}

extern "C" void kernel_launch(void* const* d_in, const int* in_sizes, int n_in,
                              void* d_out, int out_size, void* d_ws, size_t ws_size,
                              hipStream_t stream)
{
    const float* img1 = (const float*)d_in[0];
    const float* img2 = (const float*)d_in[1];
    const float* win  = (const float*)d_in[2];
    float* partials   = (float*)d_ws;
    float* out        = (float*)d_out;

    dim3 grid(GX, GY, NIMG);
    dim3 block(BX);
    ssim_main<<<grid, block, 0, stream>>>(img1, img2, win, partials);
    ssim_finalize<<<1, 256, 0, stream>>>(partials, out);
}

// Round 9
// 62.178 us; speedup vs baseline: 1.4304x; 1.4304x over previous
//
#include <hip/hip_runtime.h>

// SSIM fused: [16,1,1024,1024] fp32, 11-tap separable Gaussian.
// V-phase: 1 col/thread, register ring of 11 rows x packed float4 channels
//          {a, b, a^2+b^2, a*b}; one ds_write_b128 per pixel.
// H-phase: run = t&15 (8-col runs), q = t>>4 -> aligned 8-lane phase groups
//          hit 8 distinct bank-groups after swz() -> conflict-free b128 reads.
// Cross-barrier software prefetch: stage st+1's 16 global loads are issued
// into registers BEFORE H(st) (≈700 cy of LDS+VALU to hide HBM latency);
// V(st+1) then consumes registers only. 16 KB single-buffered LDS.
// No min-occupancy launch_bounds arg (r5/r6: it forces spills).
// Deterministic two-stage reduction -> d_out[0].

typedef float f4 __attribute__((ext_vector_type(4)));

#define W      1024
#define H      1024
#define NIMG   16
#define HALO   5
#define BX     128                 // threads = LDS slots (input cols) per block
#define OUTW   118                 // output cols per block
#define RPS    8                   // rows per stage
#define NSTG   4                   // stages per block
#define TH     (RPS*NSTG)          // 32 output rows per block
#define GX     9                   // ceil(1024/118)
#define GY     (H/TH)              // 32
#define NBLK   (GX*GY*NIMG)        // 4608

__device__ __forceinline__ int swz(int s) { return s ^ ((s >> 3) & 7); }

template<bool INT>
__device__ __forceinline__ void pf_row(const float* __restrict__ p1,
                                       const float* __restrict__ p2,
                                       int j, int c, bool cOK,
                                       float& a, float& b)
{
    if (INT) {
        a = p1[(size_t)j * W + c];
        b = p2[(size_t)j * W + c];
    } else {
        const bool ok = cOK && ((unsigned)j < H);
        a = ok ? p1[(size_t)j * W + c] : 0.0f;
        b = ok ? p2[(size_t)j * W + c] : 0.0f;
    }
}

__device__ __forceinline__ f4 pack_ch(float a, float b)
{
    f4 v;
    v.x = a; v.y = b;
    v.z = fmaf(a, a, b * b);
    v.w = a * b;
    return v;
}

// V-blur 8 rows from prefetched registers; write LDS buf.
__device__ __forceinline__ void vstage_reg(const float* __restrict__ w,
                                           const float (&pa)[RPS], const float (&pb)[RPS],
                                           f4 (&ring)[11], f4 (*buf)[BX], int ws_)
{
#pragma unroll
    for (int rr = 0; rr < RPS; ++rr) {
#pragma unroll
        for (int k = 0; k < 10; ++k) ring[k] = ring[k + 1];
        ring[10] = pack_ch(pa[rr], pb[rr]);

        f4 acc = w[5] * ring[5];
#pragma unroll
        for (int k = 0; k < 5; ++k)
            acc += w[k] * (ring[k] + ring[10 - k]);

        buf[rr][ws_] = acc;
    }
}

template<bool INT>
__device__ float tile(const float* __restrict__ p1,
                      const float* __restrict__ p2,
                      const float* __restrict__ w,
                      int cb, int r0, int t,
                      f4 (*lds)[BX])
{
    const int  c   = cb + t;                 // this thread's input col
    const bool cOK = INT || ((unsigned)c < W);

    // ring[1..10] <- rows r0-5 .. r0+4 (packed 4 channels)
    f4 ring[11];
#pragma unroll
    for (int k = 0; k < 10; ++k) {
        float a, b;
        pf_row<INT>(p1, p2, r0 - HALO + k, c, cOK, a, b);
        ring[k + 1] = pack_ch(a, b);
    }

    // h-task mapping (power-of-2, phase-group aligned)
    const int  q   = t >> 4;                 // staged row index 0..7
    const int  run = t & 15;                 // column run index
    const int  S0  = 8 * run;                // first LDS slot of run
    const bool hT  = (run < 15);             // run 15 idle in H phase
    const int  ws_ = swz(t);                 // v-phase write slot

    float pa[RPS], pb[RPS];

    // prologue: prefetch + V-blur stage 0
#pragma unroll
    for (int rr = 0; rr < RPS; ++rr)
        pf_row<INT>(p1, p2, r0 + HALO + rr, c, cOK, pa[rr], pb[rr]);
    vstage_reg(w, pa, pb, ring, lds, ws_);
    __syncthreads();

    float tsum = 0.0f;

    for (int st = 0; st < NSTG; ++st) {
        // ---- prefetch stage st+1 rows (VMEM issue; consumed after barrier) ----
        if (st + 1 < NSTG) {
#pragma unroll
            for (int rr = 0; rr < RPS; ++rr)
                pf_row<INT>(p1, p2, r0 + (st + 1) * RPS + HALO + rr, c, cOK,
                            pa[rr], pb[rr]);
        }

        // ---- H phase for current stage (hides prefetch latency) ----
        if (hT) {
            f4 o[8] = {};
#pragma unroll
            for (int i = 0; i < 18; ++i) {
                int sIdx = S0 + i;                       // run14: up to 129
                sIdx = (sIdx < BX) ? sIdx : (BX - 1);    // clamp: feeds only invalid outs
                const f4 u = lds[q][swz(sIdx)];
#pragma unroll
                for (int oo = 0; oo < 8; ++oo) {
                    const int k = i - oo;
                    if (k >= 0 && k < 11)
                        o[oo] += w[k] * u;
                }
            }

            const float C1f = 0.0001f, C2f = 0.0009f;
#pragma unroll
            for (int oo = 0; oo < 8; ++oo) {
                const int rel = S0 + oo;                 // rel output col
                const bool valid = (rel < OUTW) &&
                                   (INT || (cb + HALO + rel) < W);
                if (valid) {
                    const float m1 = o[oo].x, m2 = o[oo].y;
                    const float qq = o[oo].z, pp = o[oo].w;
                    const float mu12 = m1 * m2, m1s = m1 * m1, m2s = m2 * m2;
                    const float s12 = pp - mu12;
                    const float ssq = qq - m1s - m2s;
                    const float num = (2.f * mu12 + C1f) * (2.f * s12 + C2f);
                    const float den = (m1s + m2s + C1f) * (ssq + C2f);
                    tsum += num * __builtin_amdgcn_rcpf(den);
                }
            }
        }
        __syncthreads();                 // WAR: all H reads done before V rewrites

        // ---- V phase for next stage, from prefetched registers ----
        if (st + 1 < NSTG) {
            vstage_reg(w, pa, pb, ring, lds, ws_);
            __syncthreads();             // RAW: V writes visible to next H
        }
    }
    return tsum;
}

__global__ __launch_bounds__(BX) void ssim_main(const float* __restrict__ img1,
                                                const float* __restrict__ img2,
                                                const float* __restrict__ win,
                                                float* __restrict__ partials)
{
    __shared__ f4 lds[RPS][BX];              // 16 KB, single-buffered

    const int t  = threadIdx.x;
    const int n  = blockIdx.z;
    const int bx = blockIdx.x;
    const int gy = blockIdx.y;
    const int cb = bx * OUTW - HALO;         // input col of LDS slot 0
    const int r0 = gy * TH;

    const float* __restrict__ p1 = img1 + (size_t)n * (size_t)(W * H);
    const float* __restrict__ p2 = img2 + (size_t)n * (size_t)(W * H);

    float w[11];
#pragma unroll
    for (int k = 0; k < 11; ++k)
        w[k] = __int_as_float(__builtin_amdgcn_readfirstlane(__float_as_int(win[k])));

    const bool interior = (cb >= 0) && (cb + BX <= W) &&
                          (r0 >= HALO) && (r0 + TH - 1 + HALO < H);

    float tsum = interior ? tile<true >(p1, p2, w, cb, r0, t, lds)
                          : tile<false>(p1, p2, w, cb, r0, t, lds);

    // block reduction (2 waves of 64); reuse staging LDS as scratch
#pragma unroll
    for (int off = 32; off > 0; off >>= 1)
        tsum += __shfl_down(tsum, off, 64);

    float* red = (float*)lds;                // safe: trailing barrier in tile()
    if ((t & 63) == 0) red[t >> 6] = tsum;
    __syncthreads();
    if (t == 0)
        partials[((size_t)n * GY + gy) * GX + bx] = red[0] + red[1];
}

__global__ __launch_bounds__(256) void ssim_finalize(const float* __restrict__ partials,
                                                     float* __restrict__ out)
{
    double s = 0.0;
    for (int i = threadIdx.x; i < NBLK; i += 256) s += (double)partials[i];
#pragma unroll
    for (int off = 32; off > 0; off >>= 1)
        s += __shfl_down(s, off, 64);

    __shared__ double ws[4];
    if ((threadIdx.x & 63) == 0) ws[threadIdx.x >> 6] = s;
    __syncthreads();
    if (threadIdx.x == 0) {
        const double tt = ws[0] + ws[1] + ws[2] + ws[3];
        out[0] = (float)(tt / (double)((size_t)NIMG * W * H));
    }
}

extern "C" void kernel_launch(void* const* d_in, const int* in_sizes, int n_in,
                              void* d_out, int out_size, void* d_ws, size_t ws_size,
                              hipStream_t stream)
{
    const float* img1 = (const float*)d_in[0];
    const float* img2 = (const float*)d_in[1];
    const float* win  = (const float*)d_in[2];
    float* partials   = (float*)d_ws;
    float* out        = (float*)d_out;

    dim3 grid(GX, GY, NIMG);
    dim3 block(BX);
    ssim_main<<<grid, block, 0, stream>>>(img1, img2, win, partials);
    ssim_finalize<<<1, 256, 0, stream>>>(partials, out);
}

// Round 10
// 59.372 us; speedup vs baseline: 1.4980x; 1.0473x over previous
//
#include <hip/hip_runtime.h>

// SSIM fused: [16,1,1024,1024] fp32, 11-tap separable Gaussian.
// Two independent 128-thread halves per 256-thread block (sub = t>>7), each
// half = round-9 kernel verbatim: V-phase register ring + packed float4
// channels {a, b, a^2+b^2, a*b}; H-phase run = tt&15, q = tt>>4, swizzled
// conflict-free b128 reads; cross-barrier register prefetch of next stage's
// global loads. 32 KB LDS/block (2 x 16 KB halves) probes whether CU LDS
// residency caps at 64 KB or 160 KB. No min-occupancy launch_bounds arg
// (r5/r6: it forces spills). Deterministic two-stage reduction -> d_out[0].

typedef float f4 __attribute__((ext_vector_type(4)));

#define W      1024
#define H      1024
#define NIMG   16
#define HALO   5
#define BX     256                 // 2 halves x 128 threads
#define BXH    128                 // threads / LDS slots per half
#define OUTW   118                 // output cols per half
#define RPS    8                   // rows per stage
#define NSTG   4                   // stages per half
#define TH     (RPS*NSTG)          // 32 output rows per half
#define GX     9                   // ceil(1024/118)
#define GY     (H/(2*TH))          // 16 (each block covers 64 rows)
#define NBLK   (GX*GY*NIMG)        // 2304

__device__ __forceinline__ int swz(int s) { return s ^ ((s >> 3) & 7); }

template<bool INT>
__device__ __forceinline__ void pf_row(const float* __restrict__ p1,
                                       const float* __restrict__ p2,
                                       int j, int c, bool cOK,
                                       float& a, float& b)
{
    if (INT) {
        a = p1[(size_t)j * W + c];
        b = p2[(size_t)j * W + c];
    } else {
        const bool ok = cOK && ((unsigned)j < H);
        a = ok ? p1[(size_t)j * W + c] : 0.0f;
        b = ok ? p2[(size_t)j * W + c] : 0.0f;
    }
}

__device__ __forceinline__ f4 pack_ch(float a, float b)
{
    f4 v;
    v.x = a; v.y = b;
    v.z = fmaf(a, a, b * b);
    v.w = a * b;
    return v;
}

// V-blur 8 rows from prefetched registers; write LDS buf.
__device__ __forceinline__ void vstage_reg(const float* __restrict__ w,
                                           const float (&pa)[RPS], const float (&pb)[RPS],
                                           f4 (&ring)[11], f4 (*buf)[BXH], int ws_)
{
#pragma unroll
    for (int rr = 0; rr < RPS; ++rr) {
#pragma unroll
        for (int k = 0; k < 10; ++k) ring[k] = ring[k + 1];
        ring[10] = pack_ch(pa[rr], pb[rr]);

        f4 acc = w[5] * ring[5];
#pragma unroll
        for (int k = 0; k < 5; ++k)
            acc += w[k] * (ring[k] + ring[10 - k]);

        buf[rr][ws_] = acc;
    }
}

template<bool INT>
__device__ float tile(const float* __restrict__ p1,
                      const float* __restrict__ p2,
                      const float* __restrict__ w,
                      int cb, int r0, int tt,
                      f4 (*lds)[BXH])
{
    const int  c   = cb + tt;                // this thread's input col
    const bool cOK = INT || ((unsigned)c < W);

    // ring[1..10] <- rows r0-5 .. r0+4 (packed 4 channels)
    f4 ring[11];
#pragma unroll
    for (int k = 0; k < 10; ++k) {
        float a, b;
        pf_row<INT>(p1, p2, r0 - HALO + k, c, cOK, a, b);
        ring[k + 1] = pack_ch(a, b);
    }

    // h-task mapping (power-of-2, phase-group aligned)
    const int  q   = tt >> 4;                // staged row index 0..7
    const int  run = tt & 15;                // column run index
    const int  S0  = 8 * run;                // first LDS slot of run
    const bool hT  = (run < 15);             // run 15 idle in H phase
    const int  ws_ = swz(tt);                // v-phase write slot

    float pa[RPS], pb[RPS];

    // prologue: prefetch + V-blur stage 0
#pragma unroll
    for (int rr = 0; rr < RPS; ++rr)
        pf_row<INT>(p1, p2, r0 + HALO + rr, c, cOK, pa[rr], pb[rr]);
    vstage_reg(w, pa, pb, ring, lds, ws_);
    __syncthreads();

    float tsum = 0.0f;

    for (int st = 0; st < NSTG; ++st) {
        // ---- prefetch stage st+1 rows (VMEM issue; consumed after barrier) ----
        if (st + 1 < NSTG) {
#pragma unroll
            for (int rr = 0; rr < RPS; ++rr)
                pf_row<INT>(p1, p2, r0 + (st + 1) * RPS + HALO + rr, c, cOK,
                            pa[rr], pb[rr]);
        }

        // ---- H phase for current stage (hides prefetch latency) ----
        if (hT) {
            f4 o[8] = {};
#pragma unroll
            for (int i = 0; i < 18; ++i) {
                int sIdx = S0 + i;                       // run14: up to 129
                sIdx = (sIdx < BXH) ? sIdx : (BXH - 1);  // clamp: feeds only invalid outs
                const f4 u = lds[q][swz(sIdx)];
#pragma unroll
                for (int oo = 0; oo < 8; ++oo) {
                    const int k = i - oo;
                    if (k >= 0 && k < 11)
                        o[oo] += w[k] * u;
                }
            }

            const float C1f = 0.0001f, C2f = 0.0009f;
#pragma unroll
            for (int oo = 0; oo < 8; ++oo) {
                const int rel = S0 + oo;                 // rel output col
                const bool valid = (rel < OUTW) &&
                                   (INT || (cb + HALO + rel) < W);
                if (valid) {
                    const float m1 = o[oo].x, m2 = o[oo].y;
                    const float qq = o[oo].z, pp = o[oo].w;
                    const float mu12 = m1 * m2, m1s = m1 * m1, m2s = m2 * m2;
                    const float s12 = pp - mu12;
                    const float ssq = qq - m1s - m2s;
                    const float num = (2.f * mu12 + C1f) * (2.f * s12 + C2f);
                    const float den = (m1s + m2s + C1f) * (ssq + C2f);
                    tsum += num * __builtin_amdgcn_rcpf(den);
                }
            }
        }
        __syncthreads();                 // WAR: all H reads done before V rewrites

        // ---- V phase for next stage, from prefetched registers ----
        if (st + 1 < NSTG) {
            vstage_reg(w, pa, pb, ring, lds, ws_);
            __syncthreads();             // RAW: V writes visible to next H
        }
    }
    return tsum;
}

__global__ __launch_bounds__(BX) void ssim_main(const float* __restrict__ img1,
                                                const float* __restrict__ img2,
                                                const float* __restrict__ win,
                                                float* __restrict__ partials)
{
    __shared__ f4 lds[2][RPS][BXH];          // 32 KB: one 16 KB half per sub-block

    const int t   = threadIdx.x;
    const int sub = t >> 7;                  // which vertical half
    const int tt  = t & (BXH - 1);
    const int n   = blockIdx.z;
    const int bx  = blockIdx.x;
    const int gy  = blockIdx.y;
    const int cb  = bx * OUTW - HALO;        // input col of LDS slot 0
    const int r0  = (gy * 2 + sub) * TH;     // this half's first output row

    const float* __restrict__ p1 = img1 + (size_t)n * (size_t)(W * H);
    const float* __restrict__ p2 = img2 + (size_t)n * (size_t)(W * H);

    float w[11];
#pragma unroll
    for (int k = 0; k < 11; ++k)
        w[k] = __int_as_float(__builtin_amdgcn_readfirstlane(__float_as_int(win[k])));

    // block-uniform interior test (covers both halves)
    const int rTop = gy * 2 * TH;
    const bool interior = (cb >= 0) && (cb + BXH <= W) &&
                          (rTop >= HALO) && (rTop + 2 * TH - 1 + HALO < H);

    float tsum = interior ? tile<true >(p1, p2, w, cb, r0, tt, lds[sub])
                          : tile<false>(p1, p2, w, cb, r0, tt, lds[sub]);

    // block reduction (4 waves of 64); reuse staging LDS as scratch
#pragma unroll
    for (int off = 32; off > 0; off >>= 1)
        tsum += __shfl_down(tsum, off, 64);

    float* red = (float*)lds;                // safe: trailing barrier in tile()
    if ((t & 63) == 0) red[t >> 6] = tsum;
    __syncthreads();
    if (t == 0)
        partials[((size_t)n * GY + gy) * GX + bx] =
            (red[0] + red[1]) + (red[2] + red[3]);
}

__global__ __launch_bounds__(256) void ssim_finalize(const float* __restrict__ partials,
                                                     float* __restrict__ out)
{
    double s = 0.0;
    for (int i = threadIdx.x; i < NBLK; i += 256) s += (double)partials[i];
#pragma unroll
    for (int off = 32; off > 0; off >>= 1)
        s += __shfl_down(s, off, 64);

    __shared__ double ws[4];
    if ((threadIdx.x & 63) == 0) ws[threadIdx.x >> 6] = s;
    __syncthreads();
    if (threadIdx.x == 0) {
        const double tt = ws[0] + ws[1] + ws[2] + ws[3];
        out[0] = (float)(tt / (double)((size_t)NIMG * W * H));
    }
}

extern "C" void kernel_launch(void* const* d_in, const int* in_sizes, int n_in,
                              void* d_out, int out_size, void* d_ws, size_t ws_size,
                              hipStream_t stream)
{
    const float* img1 = (const float*)d_in[0];
    const float* img2 = (const float*)d_in[1];
    const float* win  = (const float*)d_in[2];
    float* partials   = (float*)d_ws;
    float* out        = (float*)d_out;

    dim3 grid(GX, GY, NIMG);
    dim3 block(BX);
    ssim_main<<<grid, block, 0, stream>>>(img1, img2, win, partials);
    ssim_finalize<<<1, 256, 0, stream>>>(partials, out);
}